// Round 2
// baseline (998.579 us; speedup 1.0000x reference)
//
#include <hip/hip_runtime.h>

// Masked mean-pool: out[b,d] = sum_s embed[b,s,d]*mask[b,s] / sum_s mask[b,s]
// mask[b,s] = token_ids[b,s] not in {0 (PAD), 101 (CLS), 102 (SEP)}
//
// B=512, S=512, D=768, fp32. Streaming-read bound: ~805 MB embed.
// Roofline @6.3 TB/s achievable: ~128 us.
//
// V3: V2 (4x occupancy) changed nothing -> not latency-bound. The shared
// structural feature of V1/V2 was the strided per-wave walk (1 KB slice,
// 3 KB jump) and only 512 blocks. V3 restructures to textbook streaming:
//   kernel1: grid = B*P (P=4 s-parts) = 2048 blocks x 256 threads.
//            Each of 4 waves streams 32 CONSECUTIVE rows, reading each
//            3 KB row as 3 back-to-back 1 KB wave-loads (contiguous 96 KB
//            stream per wave). Partial sums + counts -> workspace (6.3 MB).
//   kernel2: 512 blocks x 192 threads, reduce 4 partials, divide, store.

constexpr int B  = 512;
constexpr int S  = 512;
constexpr int D  = 768;
constexpr int NV = D / 4;      // 192 float4 columns per row
constexpr int P  = 4;          // s-parts per batch row
constexpr int SP = S / P;      // 128 rows per part
constexpr int WAVES = 4;       // 256 threads per block
constexpr int RW = SP / WAVES; // 32 consecutive rows per wave

__global__ __launch_bounds__(256) void partial_kernel(
    const float4* __restrict__ embed,   // [B, S, NV]
    const int*    __restrict__ tok,     // [B, S]
    float4*       __restrict__ ws_sum,  // [B*P, NV]
    float*        __restrict__ ws_cnt)  // [B*P]
{
    const int bp   = blockIdx.x;        // b*P + p
    const int b    = bp >> 2;
    const int p    = bp & (P - 1);
    const int t    = threadIdx.x;
    const int w    = t >> 6;
    const int lane = t & 63;

    __shared__ float  maskf[SP];            // 512 B
    __shared__ float4 sacc[WAVES][NV];      // 12 KB
    __shared__ float  scnt[WAVES];

    const int sbase = p * SP;

    // Stage mask for this s-part (coalesced, threads 0..127).
    if (t < SP) {
        const int id = tok[b * S + sbase + t];
        maskf[t] = (id != 0 && id != 101 && id != 102) ? 1.0f : 0.0f;
    }
    __syncthreads();

    // Wave w streams rows [r0, r0+RW): contiguous 96 KB.
    const int r0 = w * RW;
    const float4* rowp = embed + ((size_t)b * S + sbase + r0) * NV + lane;

    float4 a0 = make_float4(0.f, 0.f, 0.f, 0.f);
    float4 a1 = make_float4(0.f, 0.f, 0.f, 0.f);
    float4 a2 = make_float4(0.f, 0.f, 0.f, 0.f);
    float  cnt = 0.f;

#pragma unroll 2
    for (int r = 0; r < RW; ++r) {
        const float  m  = maskf[r0 + r];      // same-address LDS broadcast
        const float4 v0 = rowp[(size_t)r * NV];
        const float4 v1 = rowp[(size_t)r * NV + 64];
        const float4 v2 = rowp[(size_t)r * NV + 128];
        cnt += m;
        a0.x = fmaf(v0.x, m, a0.x); a0.y = fmaf(v0.y, m, a0.y);
        a0.z = fmaf(v0.z, m, a0.z); a0.w = fmaf(v0.w, m, a0.w);
        a1.x = fmaf(v1.x, m, a1.x); a1.y = fmaf(v1.y, m, a1.y);
        a1.z = fmaf(v1.z, m, a1.z); a1.w = fmaf(v1.w, m, a1.w);
        a2.x = fmaf(v2.x, m, a2.x); a2.y = fmaf(v2.y, m, a2.y);
        a2.z = fmaf(v2.z, m, a2.z); a2.w = fmaf(v2.w, m, a2.w);
    }

    sacc[w][lane]       = a0;
    sacc[w][lane + 64]  = a1;
    sacc[w][lane + 128] = a2;
    if (lane == 0) scnt[w] = cnt;
    __syncthreads();

    // Reduce 4 waves -> one partial per (b,p). Threads 0..191.
    if (t < NV) {
        float4 s0 = sacc[0][t];
        const float4 s1 = sacc[1][t];
        const float4 s2 = sacc[2][t];
        const float4 s3 = sacc[3][t];
        s0.x += s1.x + s2.x + s3.x;
        s0.y += s1.y + s2.y + s3.y;
        s0.z += s1.z + s2.z + s3.z;
        s0.w += s1.w + s2.w + s3.w;
        ws_sum[(size_t)bp * NV + t] = s0;
    }
    if (t == 0) ws_cnt[bp] = scnt[0] + scnt[1] + scnt[2] + scnt[3];
}

__global__ __launch_bounds__(NV) void finalize_kernel(
    const float4* __restrict__ ws_sum,  // [B*P, NV]
    const float*  __restrict__ ws_cnt,  // [B*P]
    float4*       __restrict__ out)     // [B, NV]
{
    const int b = blockIdx.x;
    const int t = threadIdx.x;

    float4 a = make_float4(0.f, 0.f, 0.f, 0.f);
#pragma unroll
    for (int p = 0; p < P; ++p) {
        const float4 v = ws_sum[((size_t)(b * P + p)) * NV + t];
        a.x += v.x; a.y += v.y; a.z += v.z; a.w += v.w;
    }
    const float c = ws_cnt[b * P + 0] + ws_cnt[b * P + 1]
                  + ws_cnt[b * P + 2] + ws_cnt[b * P + 3];
    const float inv = 1.0f / c;
    out[b * NV + t] = make_float4(a.x * inv, a.y * inv, a.z * inv, a.w * inv);
}

extern "C" void kernel_launch(void* const* d_in, const int* in_sizes, int n_in,
                              void* d_out, int out_size, void* d_ws, size_t ws_size,
                              hipStream_t stream) {
    const float4* embed = (const float4*)d_in[0];
    const int* tok = (const int*)d_in[1];
    float4* out = (float4*)d_out;

    // Workspace layout: [B*P][NV] float4 partial sums, then [B*P] float counts.
    float4* ws_sum = (float4*)d_ws;
    float*  ws_cnt = (float*)((char*)d_ws + (size_t)B * P * NV * sizeof(float4));

    partial_kernel<<<dim3(B * P), dim3(256), 0, stream>>>(embed, tok, ws_sum, ws_cnt);
    finalize_kernel<<<dim3(B), dim3(NV), 0, stream>>>(ws_sum, ws_cnt, out);
}